// Round 1
// baseline (707.558 us; speedup 1.0000x reference)
//
#include <hip/hip_runtime.h>

#define N_PTS 32768
#define HID   100
#define STEPS 100

// Output layout (concatenated flat, fp32):
//   z          @ 0       (N*2)
//   mu_xz      @ 65536   (N*3)
//   log_sig_xz @ 163840  (N*3)
//   mu_zx      @ 262144  (N*2)
//   log_t_zx   @ 327680  (N*1)
//   mu_z       @ 360448  (N*2)
//   log_t_z    @ 425984  (N*1)
#define OFF_Z     0
#define OFF_MUXZ  65536
#define OFF_LSXZ  163840
#define OFF_MUZX  262144
#define OFF_LTZX  327680
#define OFF_MUZ   360448
#define OFF_LTZ   425984

// Butterfly sum across a quad of lanes (lanes 4p..4p+3) via DPP quad_perm.
// 0xB1 = [1,0,3,2] (xor 1), 0x4E = [2,3,0,1] (xor 2). VALU-pipe, no LDS.
__device__ __forceinline__ float qreduce(float v) {
  v += __int_as_float(__builtin_amdgcn_update_dpp(0, __float_as_int(v), 0xB1, 0xF, 0xF, true));
  v += __int_as_float(__builtin_amdgcn_update_dpp(0, __float_as_int(v), 0x4E, 0xF, 0xF, true));
  return v;
}

// ---------------- Encoder: x -> h1 -> h2 -> (mu_zx, log_t_zx) ----------------
// Block = 128 threads = 2 waves covering 64 points; wave w handles h2 outputs
// [w*50, w*50+50). k-outer / o-inner keeps 50 accumulators in VGPRs and sweeps
// We2 row-contiguously; readfirstlane makes the weight index wave-uniform so
// the compiler emits scalar (K$) loads.
__global__ __launch_bounds__(128) void enc_kernel(
    const float* __restrict__ x,
    const float* __restrict__ We1, const float* __restrict__ be1,
    const float* __restrict__ We2, const float* __restrict__ be2,
    const float* __restrict__ Wmu, const float* __restrict__ bmu,
    const float* __restrict__ Wlt, const float* __restrict__ blt,
    const float* __restrict__ b_muz, const float* __restrict__ b_ltz,
    float* __restrict__ out)
{
  const int tid = threadIdx.x;
  const int w   = tid >> 6;           // wave 0/1
  const int pb  = tid & 63;           // point within block
  const int p   = blockIdx.x * 64 + pb;
  const int ob  = __builtin_amdgcn_readfirstlane(w * 50);

  const float x0 = x[p*3+0], x1 = x[p*3+1], x2 = x[p*3+2];

  float acc[50];
  #pragma unroll
  for (int i = 0; i < 50; ++i) acc[i] = 0.f;

  for (int k = 0; k < HID; ++k) {
    float a   = fmaf(x0, We1[k], fmaf(x1, We1[HID+k], fmaf(x2, We1[2*HID+k], be1[k])));
    float sig = 1.f / (1.f + __expf(-a));
    float h1  = a * sig;
    const float* row = We2 + k*HID + ob;
    #pragma unroll
    for (int oo = 0; oo < 50; ++oo) acc[oo] = fmaf(h1, row[oo], acc[oo]);
  }

  float m0 = 0.f, m1 = 0.f, lt = 0.f;
  #pragma unroll
  for (int oo = 0; oo < 50; ++oo) {
    const int o = ob + oo;
    float a   = acc[oo] + be2[o];
    float sig = 1.f / (1.f + __expf(-a));
    float h2  = a * sig;
    m0 = fmaf(h2, Wmu[o*2+0], m0);
    m1 = fmaf(h2, Wmu[o*2+1], m1);
    lt = fmaf(h2, Wlt[o],     lt);
  }

  __shared__ float red[2][64][3];
  red[w][pb][0] = m0; red[w][pb][1] = m1; red[w][pb][2] = lt;
  __syncthreads();
  if (w == 0) {
    m0 += red[1][pb][0] + bmu[0];
    m1 += red[1][pb][1] + bmu[1];
    lt += red[1][pb][2] + blt[0];
    out[OFF_MUZX + p*2+0] = m0;
    out[OFF_MUZX + p*2+1] = m1;
    out[OFF_LTZX + p]     = lt;
    out[OFF_MUZ  + p*2+0] = b_muz[0];
    out[OFF_MUZ  + p*2+1] = b_muz[1];
    out[OFF_LTZ  + p]     = b_ltz[0];
  }
}

// ------------- SDE: 100 Euler-Maruyama steps on the pullback metric ----------
// Block = 256 threads = 64 points, 4 lanes per point; each lane owns 25 hidden
// units. Decoder weights live in LDS as 12-float (48 B) records:
//   {Wd1[0,j], Wd1[1,j], bd1[j], Wdmu[j,0..2], Wds[j,0..2], pad x3}
// 48 B stride (12 banks) avoids power-of-2 conflicts; quad lanes read 4
// distinct records, broadcast across the 16 lanes sharing each.
__global__ __launch_bounds__(256) void sde_kernel(
    const float* __restrict__ Wd1,  const float* __restrict__ bd1,
    const float* __restrict__ Wdmu, const float* __restrict__ bdmu,
    const float* __restrict__ Wds,  const float* __restrict__ bds,
    const float* __restrict__ noise,
    float* __restrict__ out)
{
  __shared__ __align__(16) float wrec[HID*12];
  const int tid = threadIdx.x;
  for (int idx = tid; idx < HID*12; idx += 256) {
    const int j = idx / 12, f = idx - j*12;
    float v = 0.f;
    if      (f == 0) v = Wd1[j];
    else if (f == 1) v = Wd1[HID + j];
    else if (f == 2) v = bd1[j];
    else if (f < 6)  v = Wdmu[j*3 + (f-3)];
    else if (f < 9)  v = Wds [j*3 + (f-6)];
    wrec[idx] = v;
  }
  __syncthreads();

  const int l     = tid & 3;                    // lane within quad
  const int p     = blockIdx.x * 64 + (tid >> 2);
  const int jbase = l * 25;

  float z0 = out[OFF_MUZX + p*2+0];
  float z1 = out[OFF_MUZX + p*2+1];
  const float sdt = __expf(out[OFF_LTZX + p]) * 0.1f;  // sqrt(dt) = exp(lt)/sqrt(100)

  for (int step = 0; step < STEPS; ++step) {
    // J[o][k] = sum_j W[j,o]*swish'(a_j)*Wd1[k,j]
    // K[o][c] = sum_j W[j,o]*swish''(a_j)*Wd1[k,j]*Wd1[l,j], c: 0->(0,0) 1->(0,1) 2->(1,1)
    float Jm[3][2] = {}, Js[3][2] = {}, Km[3][3] = {}, Ks[3][3] = {};
    #pragma unroll 5
    for (int jj = 0; jj < 25; ++jj) {
      const float* r = &wrec[(jbase + jj)*12];
      const float4 wa = *(const float4*)(r);      // {W0, W1, b, m0}
      const float4 wb = *(const float4*)(r + 4);  // {m1, m2, s0, s1}
      const float  s2w = r[8];                    // s2
      float a   = fmaf(z0, wa.x, fmaf(z1, wa.y, wa.z));
      float e   = __expf(-a);
      float sig = __builtin_amdgcn_rcpf(1.f + e);
      float t1  = 1.f - sig;
      float u   = fmaf(a*sig, t1, sig);                           // swish'
      float u2  = (sig*t1) * fmaf(a, fmaf(-2.f, sig, 1.f), 2.f);  // swish''
      float c0 = u*wa.x,  c1 = u*wa.y;
      float r0 = u2*wa.x, r1 = u2*wa.y;
      float q00 = r0*wa.x, q01 = r0*wa.y, q11 = r1*wa.y;
      const float mw[3] = {wa.w, wb.x, wb.y};
      const float sw[3] = {wb.z, wb.w, s2w};
      #pragma unroll
      for (int o = 0; o < 3; ++o) {
        Jm[o][0] = fmaf(mw[o], c0,  Jm[o][0]);
        Jm[o][1] = fmaf(mw[o], c1,  Jm[o][1]);
        Js[o][0] = fmaf(sw[o], c0,  Js[o][0]);
        Js[o][1] = fmaf(sw[o], c1,  Js[o][1]);
        Km[o][0] = fmaf(mw[o], q00, Km[o][0]);
        Km[o][1] = fmaf(mw[o], q01, Km[o][1]);
        Km[o][2] = fmaf(mw[o], q11, Km[o][2]);
        Ks[o][0] = fmaf(sw[o], q00, Ks[o][0]);
        Ks[o][1] = fmaf(sw[o], q01, Ks[o][1]);
        Ks[o][2] = fmaf(sw[o], q11, Ks[o][2]);
      }
    }
    // complete the j-sums across the quad (linear, so reduce before products)
    #pragma unroll
    for (int o = 0; o < 3; ++o) {
      Jm[o][0]=qreduce(Jm[o][0]); Jm[o][1]=qreduce(Jm[o][1]);
      Js[o][0]=qreduce(Js[o][0]); Js[o][1]=qreduce(Js[o][1]);
      Km[o][0]=qreduce(Km[o][0]); Km[o][1]=qreduce(Km[o][1]); Km[o][2]=qreduce(Km[o][2]);
      Ks[o][0]=qreduce(Ks[o][0]); Ks[o][1]=qreduce(Ks[o][1]); Ks[o][2]=qreduce(Ks[o][2]);
    }

    // G = J^T J (2x2 sym)
    float G00=0.f, G01=0.f, G11=0.f;
    #pragma unroll
    for (int o = 0; o < 3; ++o) {
      G00 += Jm[o][0]*Jm[o][0] + Js[o][0]*Js[o][0];
      G01 += Jm[o][0]*Jm[o][1] + Js[o][0]*Js[o][1];
      G11 += Jm[o][1]*Jm[o][1] + Js[o][1]*Js[o][1];
    }
    // D[c][l] = dG[km]/dz_l (sym in k,m)
    float D00=0.f, D01=0.f, D10=0.f, D11=0.f, D20=0.f, D21=0.f;
    #pragma unroll
    for (int o = 0; o < 3; ++o) {
      D00 += 2.f*(Km[o][0]*Jm[o][0] + Ks[o][0]*Js[o][0]);
      D01 += 2.f*(Km[o][1]*Jm[o][0] + Ks[o][1]*Js[o][0]);
      D10 += Km[o][0]*Jm[o][1] + Jm[o][0]*Km[o][1] + Ks[o][0]*Js[o][1] + Js[o][0]*Ks[o][1];
      D11 += Km[o][1]*Jm[o][1] + Jm[o][0]*Km[o][2] + Ks[o][1]*Js[o][1] + Js[o][0]*Ks[o][2];
      D20 += 2.f*(Km[o][1]*Jm[o][1] + Ks[o][1]*Js[o][1]);
      D21 += 2.f*(Km[o][2]*Jm[o][1] + Ks[o][2]*Js[o][1]);
    }
    const float det = fmaf(G00, G11, -G01*G01);
    const float id  = __builtin_amdgcn_rcpf(det);
    const float i00 = G11*id, i01 = -G01*id, i11 = G00*id;
    // T[k,l,m] = Dg[k,m,l] + Dg[l,m,k] - Dg[k,l,m]
    const float T000 = D00;
    const float T001 = 2.f*D10 - D01;
    const float T010 = D01;
    const float T011 = D20;
    const float T110 = 2.f*D11 - D20;
    const float T111 = D21;
    // Chris[i][c] = 0.5 * ginv[i,m] T[k,l,m]
    const float C00 = 0.5f*(i00*T000 + i01*T001);
    const float C01 = 0.5f*(i00*T010 + i01*T011);
    const float C02 = 0.5f*(i00*T110 + i01*T111);
    const float C10 = 0.5f*(i01*T000 + i11*T001);
    const float C11 = 0.5f*(i01*T010 + i11*T011);
    const float C12 = 0.5f*(i01*T110 + i11*T111);
    // drift[i] = 0.5 * ginv[j,k] Chris[i,j,k]
    const float dr0 = 0.5f*(i00*C00 + 2.f*i01*C01 + i11*C02);
    const float dr1 = 0.5f*(i00*C10 + 2.f*i01*C11 + i11*C12);

    const float n0 = noise[(size_t)step*N_PTS*2 + p*2 + 0];
    const float n1 = noise[(size_t)step*N_PTS*2 + p*2 + 1];
    const float dw0 = sdt*n0, dw1 = sdt*n1;
    z0 += dr0 + i00*dw0 + i01*dw1;   // + ginv @ dW
    z1 += dr1 + i01*dw0 + i11*dw1;
  }

  // ---- final decode on z ----
  float macc[3] = {}, sacc[3] = {};
  #pragma unroll 5
  for (int jj = 0; jj < 25; ++jj) {
    const float* r = &wrec[(jbase + jj)*12];
    const float4 wa = *(const float4*)(r);
    const float4 wb = *(const float4*)(r + 4);
    const float  s2w = r[8];
    float a   = fmaf(z0, wa.x, fmaf(z1, wa.y, wa.z));
    float sig = __builtin_amdgcn_rcpf(1.f + __expf(-a));
    float h   = a * sig;
    const float mw[3] = {wa.w, wb.x, wb.y};
    const float sw[3] = {wb.z, wb.w, s2w};
    #pragma unroll
    for (int o = 0; o < 3; ++o) {
      macc[o] = fmaf(h, mw[o], macc[o]);
      sacc[o] = fmaf(h, sw[o], sacc[o]);
    }
  }
  #pragma unroll
  for (int o = 0; o < 3; ++o) { macc[o] = qreduce(macc[o]); sacc[o] = qreduce(sacc[o]); }

  if (l == 0) {
    out[OFF_Z + p*2+0] = z0;
    out[OFF_Z + p*2+1] = z1;
    #pragma unroll
    for (int o = 0; o < 3; ++o) {
      out[OFF_MUXZ + p*3 + o] = macc[o] + bdmu[o];
      out[OFF_LSXZ + p*3 + o] = sacc[o] + bds[o];
    }
  }
}

extern "C" void kernel_launch(void* const* d_in, const int* in_sizes, int n_in,
                              void* d_out, int out_size, void* d_ws, size_t ws_size,
                              hipStream_t stream) {
  (void)in_sizes; (void)n_in; (void)d_ws; (void)ws_size; (void)out_size;
  const float* x    = (const float*)d_in[0];
  const float* We1  = (const float*)d_in[1];
  const float* be1  = (const float*)d_in[2];
  const float* We2  = (const float*)d_in[3];
  const float* be2  = (const float*)d_in[4];
  const float* Wmu  = (const float*)d_in[5];
  const float* bmu  = (const float*)d_in[6];
  const float* Wlt  = (const float*)d_in[7];
  const float* blt  = (const float*)d_in[8];
  const float* Wd1  = (const float*)d_in[9];
  const float* bd1  = (const float*)d_in[10];
  const float* Wdmu = (const float*)d_in[11];
  const float* bdmu = (const float*)d_in[12];
  const float* Wds  = (const float*)d_in[13];
  const float* bds  = (const float*)d_in[14];
  const float* bmz  = (const float*)d_in[15];
  const float* blz  = (const float*)d_in[16];
  const float* noise= (const float*)d_in[17];
  float* out = (float*)d_out;

  enc_kernel<<<512, 128, 0, stream>>>(x, We1, be1, We2, be2, Wmu, bmu, Wlt, blt,
                                      bmz, blz, out);
  sde_kernel<<<512, 256, 0, stream>>>(Wd1, bd1, Wdmu, bdmu, Wds, bds, noise, out);
}

// Round 2
// 638.287 us; speedup vs baseline: 1.1085x; 1.1085x over previous
//
#include <hip/hip_runtime.h>

#define N_PTS 32768
#define HID   100
#define STEPS 100

// Output layout (concatenated flat, fp32):
#define OFF_Z     0
#define OFF_MUXZ  65536
#define OFF_LSXZ  163840
#define OFF_MUZX  262144
#define OFF_LTZX  327680
#define OFF_MUZ   360448
#define OFF_LTZ   425984

// Butterfly sum across a quad of lanes (lanes 4p..4p+3) via DPP quad_perm.
// 0xB1 = xor-1, 0x4E = xor-2. VALU-pipe, no LDS, no barrier.
__device__ __forceinline__ float qreduce(float v) {
  v += __int_as_float(__builtin_amdgcn_update_dpp(0, __float_as_int(v), 0xB1, 0xF, 0xF, true));
  v += __int_as_float(__builtin_amdgcn_update_dpp(0, __float_as_int(v), 0x4E, 0xF, 0xF, true));
  return v;
}

// ---------------- Encoder: x -> h1 -> h2 -> (mu_zx, log_t_zx) ----------------
// Block = 128 threads = 2 waves covering 64 points; wave w handles h2 outputs
// [w*50, w*50+50). launch_bounds(128,1): grid gives only 2 blocks/CU, so let
// the allocator have VGPRs (50 live accumulators).
__global__ __launch_bounds__(128, 1) void enc_kernel(
    const float* __restrict__ x,
    const float* __restrict__ We1, const float* __restrict__ be1,
    const float* __restrict__ We2, const float* __restrict__ be2,
    const float* __restrict__ Wmu, const float* __restrict__ bmu,
    const float* __restrict__ Wlt, const float* __restrict__ blt,
    const float* __restrict__ b_muz, const float* __restrict__ b_ltz,
    float* __restrict__ out)
{
  const int tid = threadIdx.x;
  const int w   = tid >> 6;           // wave 0/1
  const int pb  = tid & 63;           // point within block
  const int p   = blockIdx.x * 64 + pb;
  const int ob  = __builtin_amdgcn_readfirstlane(w * 50);

  const float x0 = x[p*3+0], x1 = x[p*3+1], x2 = x[p*3+2];

  float acc[50];
  #pragma unroll
  for (int i = 0; i < 50; ++i) acc[i] = 0.f;

  for (int k = 0; k < HID; ++k) {
    float a   = fmaf(x0, We1[k], fmaf(x1, We1[HID+k], fmaf(x2, We1[2*HID+k], be1[k])));
    float sig = 1.f / (1.f + __expf(-a));
    float h1  = a * sig;
    const float* row = We2 + k*HID + ob;
    #pragma unroll
    for (int oo = 0; oo < 50; ++oo) acc[oo] = fmaf(h1, row[oo], acc[oo]);
  }

  float m0 = 0.f, m1 = 0.f, lt = 0.f;
  #pragma unroll
  for (int oo = 0; oo < 50; ++oo) {
    const int o = ob + oo;
    float a   = acc[oo] + be2[o];
    float sig = 1.f / (1.f + __expf(-a));
    float h2  = a * sig;
    m0 = fmaf(h2, Wmu[o*2+0], m0);
    m1 = fmaf(h2, Wmu[o*2+1], m1);
    lt = fmaf(h2, Wlt[o],     lt);
  }

  __shared__ float red[2][64][3];
  red[w][pb][0] = m0; red[w][pb][1] = m1; red[w][pb][2] = lt;
  __syncthreads();
  if (w == 0) {
    m0 += red[1][pb][0] + bmu[0];
    m1 += red[1][pb][1] + bmu[1];
    lt += red[1][pb][2] + blt[0];
    out[OFF_MUZX + p*2+0] = m0;
    out[OFF_MUZX + p*2+1] = m1;
    out[OFF_LTZX + p]     = lt;
    out[OFF_MUZ  + p*2+0] = b_muz[0];
    out[OFF_MUZ  + p*2+1] = b_muz[1];
    out[OFF_LTZ  + p]     = b_ltz[0];
  }
}

// ------------- SDE: 100 Euler-Maruyama steps on the pullback metric ----------
// Block = 256 threads = 64 points, 4 lanes per point; each lane owns 25 hidden
// units. LDS record per j (12 floats = 48 B, non-pow2 stride, 3x ds_read_b128):
//   {Wd1[0,j], Wd1[1,j], bd1[j], W00, W01, W11, m0, m1, m2, s0, s1, s2}
// where Wab = Wd1[a,j]*Wd1[b,j] precomputed (saves 2 VALU/j in the hot loop).
// launch_bounds(256,2): grid = 512 blocks = exactly 2 blocks/CU; give the
// allocator 256 VGPRs/wave so the 30 accumulators stay in VGPRs (round-1's
// default allocation squeezed to 44 VGPRs -> AGPR ping-pong, ~2x VALU insts).
__global__ __launch_bounds__(256, 2) void sde_kernel(
    const float* __restrict__ Wd1,  const float* __restrict__ bd1,
    const float* __restrict__ Wdmu, const float* __restrict__ bdmu,
    const float* __restrict__ Wds,  const float* __restrict__ bds,
    const float* __restrict__ noise,
    float* __restrict__ out)
{
  __shared__ __align__(16) float wrec[HID*12];
  const int tid = threadIdx.x;
  for (int idx = tid; idx < HID*12; idx += 256) {
    const int j = idx / 12, f = idx - j*12;
    const float w0 = Wd1[j], w1 = Wd1[HID + j];
    float v;
    switch (f) {
      case 0:  v = w0; break;
      case 1:  v = w1; break;
      case 2:  v = bd1[j]; break;
      case 3:  v = w0*w0; break;
      case 4:  v = w0*w1; break;
      case 5:  v = w1*w1; break;
      case 6: case 7: case 8:  v = Wdmu[j*3 + (f-6)]; break;
      default: v = Wds [j*3 + (f-9)]; break;
    }
    wrec[idx] = v;
  }
  __syncthreads();

  const int l     = tid & 3;                    // lane within quad
  const int p     = blockIdx.x * 64 + (tid >> 2);
  const int jbase = l * 25;

  float z0 = out[OFF_MUZX + p*2+0];
  float z1 = out[OFF_MUZX + p*2+1];
  const float sdt = __expf(out[OFF_LTZX + p]) * 0.1f;  // sqrt(dt) = exp(lt)/sqrt(100)

  const float2* __restrict__ noise2 = (const float2*)noise;

  for (int step = 0; step < STEPS; ++step) {
    // issue the noise load early; its latency hides under the j-loop
    const float2 nz = noise2[(size_t)step*N_PTS + p];

    // J[o][k] = sum_j W[j,o]*swish'(a_j)*Wd1[k,j]
    // K[o][c] = sum_j W[j,o]*swish''(a_j)*Wab(j), c: 0->(0,0) 1->(0,1) 2->(1,1)
    float Jm[3][2] = {}, Js[3][2] = {}, Km[3][3] = {}, Ks[3][3] = {};
    #pragma unroll 5
    for (int jj = 0; jj < 25; ++jj) {
      const float* r = &wrec[(jbase + jj)*12];
      const float4 wa = *(const float4*)(r);      // {W0, W1, b, W00}
      const float4 wb = *(const float4*)(r + 4);  // {W01, W11, m0, m1}
      const float4 wc = *(const float4*)(r + 8);  // {m2, s0, s1, s2}
      float a   = fmaf(z0, wa.x, fmaf(z1, wa.y, wa.z));
      float e   = __expf(-a);
      float sig = __builtin_amdgcn_rcpf(1.f + e);
      float t1  = 1.f - sig;
      float pp  = sig * t1;
      float u   = fmaf(a, pp, sig);                          // swish'
      float u2  = pp * fmaf(a, fmaf(-2.f, sig, 1.f), 2.f);   // swish''
      float c0  = u*wa.x,  c1  = u*wa.y;
      float q00 = u2*wa.w, q01 = u2*wb.x, q11 = u2*wb.y;
      const float mw[3] = {wb.z, wb.w, wc.x};
      const float sw[3] = {wc.y, wc.z, wc.w};
      #pragma unroll
      for (int o = 0; o < 3; ++o) {
        Jm[o][0] = fmaf(mw[o], c0,  Jm[o][0]);
        Jm[o][1] = fmaf(mw[o], c1,  Jm[o][1]);
        Js[o][0] = fmaf(sw[o], c0,  Js[o][0]);
        Js[o][1] = fmaf(sw[o], c1,  Js[o][1]);
        Km[o][0] = fmaf(mw[o], q00, Km[o][0]);
        Km[o][1] = fmaf(mw[o], q01, Km[o][1]);
        Km[o][2] = fmaf(mw[o], q11, Km[o][2]);
        Ks[o][0] = fmaf(sw[o], q00, Ks[o][0]);
        Ks[o][1] = fmaf(sw[o], q01, Ks[o][1]);
        Ks[o][2] = fmaf(sw[o], q11, Ks[o][2]);
      }
    }
    // complete the j-sums across the quad (linear, so reduce before products)
    #pragma unroll
    for (int o = 0; o < 3; ++o) {
      Jm[o][0]=qreduce(Jm[o][0]); Jm[o][1]=qreduce(Jm[o][1]);
      Js[o][0]=qreduce(Js[o][0]); Js[o][1]=qreduce(Js[o][1]);
      Km[o][0]=qreduce(Km[o][0]); Km[o][1]=qreduce(Km[o][1]); Km[o][2]=qreduce(Km[o][2]);
      Ks[o][0]=qreduce(Ks[o][0]); Ks[o][1]=qreduce(Ks[o][1]); Ks[o][2]=qreduce(Ks[o][2]);
    }

    // G = J^T J (2x2 sym)
    float G00=0.f, G01=0.f, G11=0.f;
    #pragma unroll
    for (int o = 0; o < 3; ++o) {
      G00 += Jm[o][0]*Jm[o][0] + Js[o][0]*Js[o][0];
      G01 += Jm[o][0]*Jm[o][1] + Js[o][0]*Js[o][1];
      G11 += Jm[o][1]*Jm[o][1] + Js[o][1]*Js[o][1];
    }
    // D[c][l] = dG[km]/dz_l (sym in k,m)
    float D00=0.f, D01=0.f, D10=0.f, D11=0.f, D20=0.f, D21=0.f;
    #pragma unroll
    for (int o = 0; o < 3; ++o) {
      D00 += 2.f*(Km[o][0]*Jm[o][0] + Ks[o][0]*Js[o][0]);
      D01 += 2.f*(Km[o][1]*Jm[o][0] + Ks[o][1]*Js[o][0]);
      D10 += Km[o][0]*Jm[o][1] + Jm[o][0]*Km[o][1] + Ks[o][0]*Js[o][1] + Js[o][0]*Ks[o][1];
      D11 += Km[o][1]*Jm[o][1] + Jm[o][0]*Km[o][2] + Ks[o][1]*Js[o][1] + Js[o][0]*Ks[o][2];
      D20 += 2.f*(Km[o][1]*Jm[o][1] + Ks[o][1]*Js[o][1]);
      D21 += 2.f*(Km[o][2]*Jm[o][1] + Ks[o][2]*Js[o][1]);
    }
    const float det = fmaf(G00, G11, -G01*G01);
    const float id  = __builtin_amdgcn_rcpf(det);
    const float i00 = G11*id, i01 = -G01*id, i11 = G00*id;
    // T[k,l,m] = Dg[k,m,l] + Dg[l,m,k] - Dg[k,l,m]
    const float T000 = D00;
    const float T001 = 2.f*D10 - D01;
    const float T010 = D01;
    const float T011 = D20;
    const float T110 = 2.f*D11 - D20;
    const float T111 = D21;
    // Chris[i][c] = 0.5 * ginv[i,m] T[k,l,m]
    const float C00 = 0.5f*(i00*T000 + i01*T001);
    const float C01 = 0.5f*(i00*T010 + i01*T011);
    const float C02 = 0.5f*(i00*T110 + i01*T111);
    const float C10 = 0.5f*(i01*T000 + i11*T001);
    const float C11 = 0.5f*(i01*T010 + i11*T011);
    const float C12 = 0.5f*(i01*T110 + i11*T111);
    // drift[i] = 0.5 * ginv[j,k] Chris[i,j,k]
    const float dr0 = 0.5f*(i00*C00 + 2.f*i01*C01 + i11*C02);
    const float dr1 = 0.5f*(i00*C10 + 2.f*i01*C11 + i11*C12);

    const float dw0 = sdt*nz.x, dw1 = sdt*nz.y;
    z0 += dr0 + i00*dw0 + i01*dw1;   // + ginv @ dW
    z1 += dr1 + i01*dw0 + i11*dw1;
  }

  // ---- final decode on z ----
  float macc[3] = {}, sacc[3] = {};
  #pragma unroll 5
  for (int jj = 0; jj < 25; ++jj) {
    const float* r = &wrec[(jbase + jj)*12];
    const float4 wa = *(const float4*)(r);      // {W0, W1, b, W00}
    const float4 wb = *(const float4*)(r + 4);  // {W01, W11, m0, m1}
    const float4 wc = *(const float4*)(r + 8);  // {m2, s0, s1, s2}
    float a   = fmaf(z0, wa.x, fmaf(z1, wa.y, wa.z));
    float sig = __builtin_amdgcn_rcpf(1.f + __expf(-a));
    float h   = a * sig;
    const float mw[3] = {wb.z, wb.w, wc.x};
    const float sw[3] = {wc.y, wc.z, wc.w};
    #pragma unroll
    for (int o = 0; o < 3; ++o) {
      macc[o] = fmaf(h, mw[o], macc[o]);
      sacc[o] = fmaf(h, sw[o], sacc[o]);
    }
  }
  #pragma unroll
  for (int o = 0; o < 3; ++o) { macc[o] = qreduce(macc[o]); sacc[o] = qreduce(sacc[o]); }

  if (l == 0) {
    out[OFF_Z + p*2+0] = z0;
    out[OFF_Z + p*2+1] = z1;
    #pragma unroll
    for (int o = 0; o < 3; ++o) {
      out[OFF_MUXZ + p*3 + o] = macc[o] + bdmu[o];
      out[OFF_LSXZ + p*3 + o] = sacc[o] + bds[o];
    }
  }
}

extern "C" void kernel_launch(void* const* d_in, const int* in_sizes, int n_in,
                              void* d_out, int out_size, void* d_ws, size_t ws_size,
                              hipStream_t stream) {
  (void)in_sizes; (void)n_in; (void)d_ws; (void)ws_size; (void)out_size;
  const float* x    = (const float*)d_in[0];
  const float* We1  = (const float*)d_in[1];
  const float* be1  = (const float*)d_in[2];
  const float* We2  = (const float*)d_in[3];
  const float* be2  = (const float*)d_in[4];
  const float* Wmu  = (const float*)d_in[5];
  const float* bmu  = (const float*)d_in[6];
  const float* Wlt  = (const float*)d_in[7];
  const float* blt  = (const float*)d_in[8];
  const float* Wd1  = (const float*)d_in[9];
  const float* bd1  = (const float*)d_in[10];
  const float* Wdmu = (const float*)d_in[11];
  const float* bdmu = (const float*)d_in[12];
  const float* Wds  = (const float*)d_in[13];
  const float* bds  = (const float*)d_in[14];
  const float* bmz  = (const float*)d_in[15];
  const float* blz  = (const float*)d_in[16];
  const float* noise= (const float*)d_in[17];
  float* out = (float*)d_out;

  enc_kernel<<<512, 128, 0, stream>>>(x, We1, be1, We2, be2, Wmu, bmu, Wlt, blt,
                                      bmz, blz, out);
  sde_kernel<<<512, 256, 0, stream>>>(Wd1, bd1, Wdmu, bdmu, Wds, bds, noise, out);
}

// Round 3
// 619.706 us; speedup vs baseline: 1.1418x; 1.0300x over previous
//
#include <hip/hip_runtime.h>

#define N_PTS 32768
#define HID   100
#define STEPS 100

// Output layout (concatenated flat, fp32):
#define OFF_Z     0
#define OFF_MUXZ  65536
#define OFF_LSXZ  163840
#define OFF_MUZX  262144
#define OFF_LTZX  327680
#define OFF_MUZ   360448
#define OFF_LTZ   425984

typedef float v2f __attribute__((ext_vector_type(2)));

#if __has_builtin(__builtin_elementwise_fma)
#define FMA2(a, b, c) __builtin_elementwise_fma((a), (b), (c))
#else
#define FMA2(a, b, c) ((a) * (b) + (c))   // hipcc default ffp-contract fuses
#endif

__device__ __forceinline__ v2f splat(float x) { v2f r; r.x = x; r.y = x; return r; }

// Butterfly sum across a quad of lanes via DPP quad_perm (xor1=0xB1, xor2=0x4E).
__device__ __forceinline__ float qreduce(float v) {
  v += __int_as_float(__builtin_amdgcn_update_dpp(0, __float_as_int(v), 0xB1, 0xF, 0xF, true));
  v += __int_as_float(__builtin_amdgcn_update_dpp(0, __float_as_int(v), 0x4E, 0xF, 0xF, true));
  return v;
}
__device__ __forceinline__ v2f qreduce2(v2f v) {
  v2f r; r.x = qreduce(v.x); r.y = qreduce(v.y); return r;
}

// ---------------- Encoder: x -> h1 -> h2 -> (mu_zx, log_t_zx) ----------------
// Block = 128 threads = 2 waves covering 64 points; wave w handles h2 outputs
// [w*50, w*50+50). Inner loop: 25 v_pk_fma_f32 (paired accumulators).
__global__ __launch_bounds__(128, 1) void enc_kernel(
    const float* __restrict__ x,
    const float* __restrict__ We1, const float* __restrict__ be1,
    const float* __restrict__ We2, const float* __restrict__ be2,
    const float* __restrict__ Wmu, const float* __restrict__ bmu,
    const float* __restrict__ Wlt, const float* __restrict__ blt,
    const float* __restrict__ b_muz, const float* __restrict__ b_ltz,
    float* __restrict__ out)
{
  const int tid = threadIdx.x;
  const int w   = tid >> 6;           // wave 0/1
  const int pb  = tid & 63;           // point within block
  const int p   = blockIdx.x * 64 + pb;
  const int ob  = __builtin_amdgcn_readfirstlane(w * 50);

  const float x0 = x[p*3+0], x1 = x[p*3+1], x2 = x[p*3+2];

  v2f acc2[25];
  #pragma unroll
  for (int i = 0; i < 25; ++i) { acc2[i].x = 0.f; acc2[i].y = 0.f; }

  for (int k = 0; k < HID; ++k) {
    float a   = fmaf(x0, We1[k], fmaf(x1, We1[HID+k], fmaf(x2, We1[2*HID+k], be1[k])));
    float sig = 1.f / (1.f + __expf(-a));
    float h1  = a * sig;
    const v2f hh = splat(h1);
    const v2f* row2 = (const v2f*)(We2 + k*HID + ob);   // 8B-aligned (k*100+ob even)
    #pragma unroll
    for (int oo = 0; oo < 25; ++oo) acc2[oo] = FMA2(hh, row2[oo], acc2[oo]);
  }

  float m0 = 0.f, m1 = 0.f, lt = 0.f;
  #pragma unroll
  for (int oo = 0; oo < 25; ++oo) {
    #pragma unroll
    for (int h = 0; h < 2; ++h) {
      const int o = ob + 2*oo + h;
      float a   = (h ? acc2[oo].y : acc2[oo].x) + be2[o];
      float sig = 1.f / (1.f + __expf(-a));
      float h2  = a * sig;
      m0 = fmaf(h2, Wmu[o*2+0], m0);
      m1 = fmaf(h2, Wmu[o*2+1], m1);
      lt = fmaf(h2, Wlt[o],     lt);
    }
  }

  __shared__ float red[2][64][3];
  red[w][pb][0] = m0; red[w][pb][1] = m1; red[w][pb][2] = lt;
  __syncthreads();
  if (w == 0) {
    m0 += red[1][pb][0] + bmu[0];
    m1 += red[1][pb][1] + bmu[1];
    lt += red[1][pb][2] + blt[0];
    out[OFF_MUZX + p*2+0] = m0;
    out[OFF_MUZX + p*2+1] = m1;
    out[OFF_LTZX + p]     = lt;
    out[OFF_MUZ  + p*2+0] = b_muz[0];
    out[OFF_MUZ  + p*2+1] = b_muz[1];
    out[OFF_LTZ  + p]     = b_ltz[0];
  }
}

// ------------- SDE: 100 Euler-Maruyama steps on the pullback metric ----------
// Block = 256 threads = 64 points, 4 lanes per point; each lane owns 25 hidden
// units. LDS record per j (12 floats = 48 B, non-pow2 stride, 3x ds_read_b128):
//   {W0, W1, b, W00, W01, W11, m0, s0, m1, s1, m2, s2}
// (m_o, s_o) adjacent so the K2 accumulator consumes the loaded pair directly
// and m/s broadcasts fold into v_pk op_sel. All 30 j-sums live as 15 float2
// accumulators updated by v_pk_fma_f32 (2 FMAs per instruction).
__global__ __launch_bounds__(256, 2) void sde_kernel(
    const float* __restrict__ Wd1,  const float* __restrict__ bd1,
    const float* __restrict__ Wdmu, const float* __restrict__ bdmu,
    const float* __restrict__ Wds,  const float* __restrict__ bds,
    const float* __restrict__ noise,
    float* __restrict__ out)
{
  __shared__ __align__(16) float wrec[HID*12];
  const int tid = threadIdx.x;
  for (int idx = tid; idx < HID*12; idx += 256) {
    const int j = idx / 12, f = idx - j*12;
    const float w0 = Wd1[j], w1 = Wd1[HID + j];
    float v;
    switch (f) {
      case 0:  v = w0; break;
      case 1:  v = w1; break;
      case 2:  v = bd1[j]; break;
      case 3:  v = w0*w0; break;
      case 4:  v = w0*w1; break;
      case 5:  v = w1*w1; break;
      case 6:  v = Wdmu[j*3+0]; break;
      case 7:  v = Wds [j*3+0]; break;
      case 8:  v = Wdmu[j*3+1]; break;
      case 9:  v = Wds [j*3+1]; break;
      case 10: v = Wdmu[j*3+2]; break;
      default: v = Wds [j*3+2]; break;
    }
    wrec[idx] = v;
  }
  __syncthreads();

  const int l     = tid & 3;                    // lane within quad
  const int p     = blockIdx.x * 64 + (tid >> 2);
  const int jbase = l * 25;

  float z0 = out[OFF_MUZX + p*2+0];
  float z1 = out[OFF_MUZX + p*2+1];
  const float sdt = __expf(out[OFF_LTZX + p]) * 0.1f;  // sqrt(dt) = exp(lt)/sqrt(100)

  const float2* __restrict__ noise2 = (const float2*)noise;

  for (int step = 0; step < STEPS; ++step) {
    // issue the noise load early; its latency hides under the j-loop
    const float2 nz = noise2[(size_t)step*N_PTS + p];

    // Paired j-sums: Jm2[o]={Jm[o][0],Jm[o][1]}, Km01[o]={Km[o][0],Km[o][1]},
    // K2[o]={Km[o][2],Ks[o][2]} (consumes the (m_o,s_o) pair as-is).
    v2f Jm2[3], Js2[3], Km01[3], Ks01[3], K2[3];
    #pragma unroll
    for (int o = 0; o < 3; ++o) {
      Jm2[o]=splat(0.f); Js2[o]=splat(0.f);
      Km01[o]=splat(0.f); Ks01[o]=splat(0.f); K2[o]=splat(0.f);
    }

    #pragma unroll 5
    for (int jj = 0; jj < 25; ++jj) {
      const float* r = &wrec[(jbase + jj)*12];
      const float4 wa = *(const float4*)(r);      // {W0, W1, b, W00}
      const float4 wb = *(const float4*)(r + 4);  // {W01, W11, m0, s0}
      const float4 wc = *(const float4*)(r + 8);  // {m1, s1, m2, s2}
      float a   = fmaf(z0, wa.x, fmaf(z1, wa.y, wa.z));
      float e   = __expf(-a);
      float sig = __builtin_amdgcn_rcpf(1.f + e);
      float t1  = 1.f - sig;
      float pp  = sig * t1;
      float u   = fmaf(a, pp, sig);                          // swish'
      float u2  = pp * fmaf(a, fmaf(-2.f, sig, 1.f), 2.f);   // swish''
      v2f w01;   w01.x = wa.x;  w01.y = wa.y;
      v2f w0011; w0011.x = wa.w; w0011.y = wb.x;
      v2f c01   = splat(u)  * w01;     // {u*W0,  u*W1}
      v2f q0001 = splat(u2) * w0011;   // {u2*W00, u2*W01}
      v2f q11s  = splat(u2 * wb.y);    // {u2*W11, u2*W11}
      v2f ws[3];
      ws[0].x = wb.z; ws[0].y = wb.w;
      ws[1].x = wc.x; ws[1].y = wc.y;
      ws[2].x = wc.z; ws[2].y = wc.w;
      #pragma unroll
      for (int o = 0; o < 3; ++o) {
        const v2f mo = splat(ws[o].x);   // op_sel lo broadcast
        const v2f so = splat(ws[o].y);   // op_sel hi broadcast
        Jm2[o]  = FMA2(mo, c01,   Jm2[o]);
        Js2[o]  = FMA2(so, c01,   Js2[o]);
        Km01[o] = FMA2(mo, q0001, Km01[o]);
        Ks01[o] = FMA2(so, q0001, Ks01[o]);
        K2[o]   = FMA2(ws[o], q11s, K2[o]);
      }
    }

    // complete the j-sums across the quad (linear, so reduce before products)
    float Jm[3][2], Js[3][2], Km[3][3], Ks[3][3];
    #pragma unroll
    for (int o = 0; o < 3; ++o) {
      v2f t;
      t = qreduce2(Jm2[o]);  Jm[o][0]=t.x; Jm[o][1]=t.y;
      t = qreduce2(Js2[o]);  Js[o][0]=t.x; Js[o][1]=t.y;
      t = qreduce2(Km01[o]); Km[o][0]=t.x; Km[o][1]=t.y;
      t = qreduce2(Ks01[o]); Ks[o][0]=t.x; Ks[o][1]=t.y;
      t = qreduce2(K2[o]);   Km[o][2]=t.x; Ks[o][2]=t.y;
    }

    // G = J^T J (2x2 sym)
    float G00=0.f, G01=0.f, G11=0.f;
    #pragma unroll
    for (int o = 0; o < 3; ++o) {
      G00 += Jm[o][0]*Jm[o][0] + Js[o][0]*Js[o][0];
      G01 += Jm[o][0]*Jm[o][1] + Js[o][0]*Js[o][1];
      G11 += Jm[o][1]*Jm[o][1] + Js[o][1]*Js[o][1];
    }
    // D[c][l] = dG[km]/dz_l (sym in k,m)
    float D00=0.f, D01=0.f, D10=0.f, D11=0.f, D20=0.f, D21=0.f;
    #pragma unroll
    for (int o = 0; o < 3; ++o) {
      D00 += 2.f*(Km[o][0]*Jm[o][0] + Ks[o][0]*Js[o][0]);
      D01 += 2.f*(Km[o][1]*Jm[o][0] + Ks[o][1]*Js[o][0]);
      D10 += Km[o][0]*Jm[o][1] + Jm[o][0]*Km[o][1] + Ks[o][0]*Js[o][1] + Js[o][0]*Ks[o][1];
      D11 += Km[o][1]*Jm[o][1] + Jm[o][0]*Km[o][2] + Ks[o][1]*Js[o][1] + Js[o][0]*Ks[o][2];
      D20 += 2.f*(Km[o][1]*Jm[o][1] + Ks[o][1]*Js[o][1]);
      D21 += 2.f*(Km[o][2]*Jm[o][1] + Ks[o][2]*Js[o][1]);
    }
    const float det = fmaf(G00, G11, -G01*G01);
    const float id  = __builtin_amdgcn_rcpf(det);
    const float i00 = G11*id, i01 = -G01*id, i11 = G00*id;
    // T[k,l,m] = Dg[k,m,l] + Dg[l,m,k] - Dg[k,l,m]
    const float T000 = D00;
    const float T001 = 2.f*D10 - D01;
    const float T010 = D01;
    const float T011 = D20;
    const float T110 = 2.f*D11 - D20;
    const float T111 = D21;
    // Chris[i][c] = 0.5 * ginv[i,m] T[k,l,m]
    const float C00 = 0.5f*(i00*T000 + i01*T001);
    const float C01 = 0.5f*(i00*T010 + i01*T011);
    const float C02 = 0.5f*(i00*T110 + i01*T111);
    const float C10 = 0.5f*(i01*T000 + i11*T001);
    const float C11 = 0.5f*(i01*T010 + i11*T011);
    const float C12 = 0.5f*(i01*T110 + i11*T111);
    // drift[i] = 0.5 * ginv[j,k] Chris[i,j,k]
    const float dr0 = 0.5f*(i00*C00 + 2.f*i01*C01 + i11*C02);
    const float dr1 = 0.5f*(i00*C10 + 2.f*i01*C11 + i11*C12);

    const float dw0 = sdt*nz.x, dw1 = sdt*nz.y;
    z0 += dr0 + i00*dw0 + i01*dw1;   // + ginv @ dW
    z1 += dr1 + i01*dw0 + i11*dw1;
  }

  // ---- final decode on z ----
  v2f MS[3]; MS[0]=splat(0.f); MS[1]=splat(0.f); MS[2]=splat(0.f);
  #pragma unroll 5
  for (int jj = 0; jj < 25; ++jj) {
    const float* r = &wrec[(jbase + jj)*12];
    const float4 wa = *(const float4*)(r);      // {W0, W1, b, W00}
    const float4 wb = *(const float4*)(r + 4);  // {W01, W11, m0, s0}
    const float4 wc = *(const float4*)(r + 8);  // {m1, s1, m2, s2}
    float a   = fmaf(z0, wa.x, fmaf(z1, wa.y, wa.z));
    float sig = __builtin_amdgcn_rcpf(1.f + __expf(-a));
    float h   = a * sig;
    const v2f hh = splat(h);
    v2f ws0; ws0.x = wb.z; ws0.y = wb.w;
    v2f ws1; ws1.x = wc.x; ws1.y = wc.y;
    v2f ws2; ws2.x = wc.z; ws2.y = wc.w;
    MS[0] = FMA2(hh, ws0, MS[0]);
    MS[1] = FMA2(hh, ws1, MS[1]);
    MS[2] = FMA2(hh, ws2, MS[2]);
  }
  #pragma unroll
  for (int o = 0; o < 3; ++o) MS[o] = qreduce2(MS[o]);

  if (l == 0) {
    out[OFF_Z + p*2+0] = z0;
    out[OFF_Z + p*2+1] = z1;
    #pragma unroll
    for (int o = 0; o < 3; ++o) {
      out[OFF_MUXZ + p*3 + o] = MS[o].x + bdmu[o];
      out[OFF_LSXZ + p*3 + o] = MS[o].y + bds[o];
    }
  }
}

extern "C" void kernel_launch(void* const* d_in, const int* in_sizes, int n_in,
                              void* d_out, int out_size, void* d_ws, size_t ws_size,
                              hipStream_t stream) {
  (void)in_sizes; (void)n_in; (void)d_ws; (void)ws_size; (void)out_size;
  const float* x    = (const float*)d_in[0];
  const float* We1  = (const float*)d_in[1];
  const float* be1  = (const float*)d_in[2];
  const float* We2  = (const float*)d_in[3];
  const float* be2  = (const float*)d_in[4];
  const float* Wmu  = (const float*)d_in[5];
  const float* bmu  = (const float*)d_in[6];
  const float* Wlt  = (const float*)d_in[7];
  const float* blt  = (const float*)d_in[8];
  const float* Wd1  = (const float*)d_in[9];
  const float* bd1  = (const float*)d_in[10];
  const float* Wdmu = (const float*)d_in[11];
  const float* bdmu = (const float*)d_in[12];
  const float* Wds  = (const float*)d_in[13];
  const float* bds  = (const float*)d_in[14];
  const float* bmz  = (const float*)d_in[15];
  const float* blz  = (const float*)d_in[16];
  const float* noise= (const float*)d_in[17];
  float* out = (float*)d_out;

  enc_kernel<<<512, 128, 0, stream>>>(x, We1, be1, We2, be2, Wmu, bmu, Wlt, blt,
                                      bmz, blz, out);
  sde_kernel<<<512, 256, 0, stream>>>(Wd1, bd1, Wdmu, bdmu, Wds, bds, noise, out);
}